// Round 14
// baseline (418.782 us; speedup 1.0000x reference)
//
#include <hip/hip_runtime.h>

#define N_NODES 16384
#define N_EDGES 262144
#define HID 512
#define NG 256
#define NL 4
#define NOUT 128

typedef __attribute__((ext_vector_type(8))) short bf16x8;
typedef __attribute__((ext_vector_type(4))) float f32x4;
typedef __attribute__((ext_vector_type(8))) unsigned short u16x8;

static __device__ __forceinline__ unsigned short f2bf(float f) {
    unsigned int u = __float_as_uint(f);
    unsigned int r = (u + 0x7fffu + ((u >> 16) & 1u)) >> 16;
    return (unsigned short)r;
}
static __device__ __forceinline__ float bf2f(unsigned short s) {
    return __uint_as_float(((unsigned int)s) << 16);
}
// pack 4 floats -> 4 fp8 e4m3 bytes in a u32 (HW cvt)
static __device__ __forceinline__ unsigned int f8pk4(float a, float b, float c, float d) {
    int r = __builtin_amdgcn_cvt_pk_fp8_f32(a, b, 0, false);
    r = __builtin_amdgcn_cvt_pk_fp8_f32(c, d, r, true);
    return (unsigned int)r;
}
// decode 4+4 fp8 bytes (two u32 words) and accumulate into a[0..3] (literal selectors)
static __device__ __forceinline__ void dec8(unsigned int wa, unsigned int wb, float* a) {
    a[0] += __builtin_amdgcn_cvt_f32_fp8(wa, 0) + __builtin_amdgcn_cvt_f32_fp8(wb, 0);
    a[1] += __builtin_amdgcn_cvt_f32_fp8(wa, 1) + __builtin_amdgcn_cvt_f32_fp8(wb, 1);
    a[2] += __builtin_amdgcn_cvt_f32_fp8(wa, 2) + __builtin_amdgcn_cvt_f32_fp8(wb, 2);
    a[3] += __builtin_amdgcn_cvt_f32_fp8(wa, 3) + __builtin_amdgcn_cvt_f32_fp8(wb, 3);
}

// async 16B global -> LDS (wave-uniform LDS base + lane*16, per-lane global src)
static __device__ __forceinline__ void gload_lds16(const unsigned short* g, unsigned short* l) {
    __builtin_amdgcn_global_load_lds(
        (const __attribute__((address_space(1))) unsigned int*)(g),
        (__attribute__((address_space(3))) unsigned int*)(l), 16, 0, 0);
}

// ---------------- Fused prep: atom | count | wt | combo | gstart ----------------
__global__ __launch_bounds__(256) void k_prep(const int* __restrict__ hn, const float* __restrict__ aemb,
                                              unsigned short* __restrict__ h_bf,
                                              unsigned char* __restrict__ h_f8,
                                              const int* __restrict__ dst, int* __restrict__ cnt,
                                              const float* __restrict__ W, unsigned short* __restrict__ Wt,
                                              const float* __restrict__ bemb, unsigned char* __restrict__ ctab8,
                                              const int* __restrict__ gid, int* __restrict__ gs,
                                              float* __restrict__ rcnt) {
    const int bid = blockIdx.x;
    const int tid = threadIdx.x;
    if (bid < 8192) {  // ---- atom encoder: 2 nodes/block
        int n = bid * 2 + (tid >> 7);
        int c = (tid & 127) * 4;
        float4 acc = make_float4(0.f, 0.f, 0.f, 0.f);
        for (int f = 0; f < 9; ++f) {
            int v = hn[n * 9 + f];
            const float4 ev = *(const float4*)(aemb + (size_t)(f * 128 + v) * HID + c);
            acc.x += ev.x; acc.y += ev.y; acc.z += ev.z; acc.w += ev.w;
        }
        ushort4 pk;
        pk.x = f2bf(acc.x); pk.y = f2bf(acc.y); pk.z = f2bf(acc.z); pk.w = f2bf(acc.w);
        *(ushort4*)(h_bf + (size_t)n * HID + c) = pk;
        *(unsigned int*)(h_f8 + (size_t)n * HID + c) = f8pk4(acc.x, acc.y, acc.z, acc.w);
    } else if (bid < 9216) {  // ---- indegree count
        int e = (bid - 8192) * 256 + tid;
        atomicAdd(&cnt[dst[e]], 1);
    } else if (bid < 13312) {  // ---- W transpose + bf16
        int id = (bid - 9216) * 256 + tid;
        int l = id >> 18;
        int n = (id >> 9) & 511;
        int k = id & 511;
        Wt[id] = f2bf(W[((size_t)l << 18) + ((size_t)k << 9) + n]);
    } else if (bid < 17408) {  // ---- bond combo table (fp8)
        int id = (bid - 13312) * 256 + tid;
        int c = id & 511;
        int combo = (id >> 9) & 511;
        int l = id >> 18;
        int i0 = combo >> 6, i1 = (combo >> 3) & 7, i2 = combo & 7;
        const float* bl = bemb + (size_t)l * 3 * 8 * HID;
        float v = bl[(size_t)i0 * HID + c] + bl[(size_t)(8 + i1) * HID + c] + bl[(size_t)(16 + i2) * HID + c];
        int w = __builtin_amdgcn_cvt_pk_fp8_f32(v, 0.f, 0, false);
        ctab8[id] = (unsigned char)(w & 0xff);
    } else {  // ---- graph segment starts (gid sorted)
        int g = tid;
        int lo = 0, hi = N_NODES;
        while (lo < hi) { int mid = (lo + hi) >> 1; if (gid[mid] < g) lo = mid + 1; else hi = mid; }
        gs[g] = lo;
        if (g == 0) gs[NG] = N_NODES;
        __syncthreads();
        int e = (g == NG - 1) ? N_NODES : gs[g + 1];
        rcnt[g] = 1.0f / fmaxf((float)(e - lo), 1.0f);
    }
}

__global__ void k_scan(const int* __restrict__ cnt, int* __restrict__ rs) {
    __shared__ int spre[256];
    int t = threadIdx.x;
    int base = t * 64;
    int s = 0;
    for (int i = 0; i < 64; ++i) s += cnt[base + i];
    spre[t] = s;
    __syncthreads();
    if (t == 0) {
        int run = 0;
        for (int i = 0; i < 256; ++i) { int v = spre[i]; spre[i] = run; run += v; }
        rs[N_NODES] = run;
    }
    __syncthreads();
    int run = spre[t];
    for (int i = 0; i < 64; ++i) { rs[base + i] = run; run += cnt[base + i]; }
}

// fill CSR slots with packed edge records as fp8-ROW BYTE OFFSETS (src*512, combo*512)
__global__ void k_fillep(const int* __restrict__ dst, const int* __restrict__ rs,
                         int* __restrict__ fc, const int* __restrict__ src,
                         const int* __restrict__ hedge, int2* __restrict__ ep) {
    int e = blockIdx.x * 256 + threadIdx.x;
    int d = dst[e];
    int pos = atomicAdd(&fc[d], 1);
    int s = src[e];
    int c = hedge[e * 3 + 0] * 64 + hedge[e * 3 + 1] * 8 + hedge[e * 3 + 2];
    ep[rs[d] + pos] = make_int2(s << 9, c << 9);  // 512 B/row in fp8
}

// ---------------- Neighbor aggregate: fp8 gathers, 2 slices x 256 ch, unroll-4 ----------------
// slice s -> XCDs {4s..4s+3} (bid%8 round-robin heuristic); per-XCD-quad working set
// = 16384 x 256 x 1B = 4 MB. One node per wave: 64 lanes = 4 edge-slots x 16 ch-lanes
// (16 fp8 ch per lane). Self-term + output stay bf16.
#define EDGE1(P)                                                           \
    {                                                                      \
        uint4 wa = *(const uint4*)(h8 + (unsigned)((P).x + cb));           \
        uint4 wb = *(const uint4*)(c8 + (unsigned)((P).y + cb));           \
        dec8(wa.x, wb.x, acc);                                             \
        dec8(wa.y, wb.y, acc + 4);                                         \
        dec8(wa.z, wb.z, acc + 8);                                         \
        dec8(wa.w, wb.w, acc + 12);                                        \
    }

__global__ __launch_bounds__(256) void k_neigh(const unsigned char* __restrict__ h_f8,
                                               const unsigned short* __restrict__ h_bf,
                                               const int2* __restrict__ ep,
                                               const int* __restrict__ rs,
                                               const unsigned char* __restrict__ ctab8,
                                               unsigned short* __restrict__ t) {
    int bid = blockIdx.x;
    int slice = (bid >> 2) & 1;            // slice0 -> XCDs 0-3, slice1 -> 4-7
    int ng = (bid >> 3) * 4 + (bid & 3);   // node-group 0..4095
    int wave = threadIdx.x >> 6;
    int lane = threadIdx.x & 63;
    int eo = lane >> 4;                    // edge slot 0..3
    int cl = lane & 15;                    // channel lane (16 fp8 ch each)
    int n = ng * 4 + wave;
    int cb = slice * 256 + cl * 16;        // byte offset within 512B fp8 row
    const unsigned char* h8 = h_f8;
    const unsigned char* c8 = ctab8;
    int s = rs[n], e = rs[n + 1];
    float acc[16] = {};
    int j = s + eo;
    for (; j + 12 < e; j += 16) {  // unroll-4: slots j, j+4, j+8, j+12
        int2 p0 = ep[j];
        int2 p1 = ep[j + 4];
        int2 p2 = ep[j + 8];
        int2 p3 = ep[j + 12];
        EDGE1(p0)
        EDGE1(p1)
        EDGE1(p2)
        EDGE1(p3)
    }
    for (; j < e; j += 4) {
        int2 p = ep[j];
        EDGE1(p)
    }
    // reduce the 4 edge-slot groups (lanes differing in bits 4,5)
    #pragma unroll
    for (int q = 0; q < 16; ++q) {
        acc[q] += __shfl_xor(acc[q], 16, 64);
        acc[q] += __shfl_xor(acc[q], 32, 64);
    }
    if (eo == 0) {
        size_t ob = (size_t)n * 1024 + slice * 512 + cl * 32;  // bf16 byte offset
        u16x8 hs0 = *(const u16x8*)((const char*)h_bf + ob);
        u16x8 hs1 = *(const u16x8*)((const char*)h_bf + ob + 16);
        float inv = 1.0f / fmaxf((float)(e - s), 1.0f);
        u16x8 pk0, pk1;
        #pragma unroll
        for (int q = 0; q < 8; ++q) {
            pk0[q] = f2bf(bf2f(hs0[q]) + acc[q] * inv);
            pk1[q] = f2bf(bf2f(hs1[q]) + acc[8 + q] * inv);
        }
        *(u16x8*)((char*)t + ob) = pk0;
        *(u16x8*)((char*)t + ob + 16) = pk1;
    }
}

// ---------------- GEMM: r_bf[M,512] = bf16(A @ W + bias), 128x128 tile ----------------
#define BM 128
#define BN 128
#define BK 64

__global__ __launch_bounds__(256) void k_gemm(const unsigned short* __restrict__ A,
                                              const unsigned short* __restrict__ Bt,
                                              const float* __restrict__ bias,
                                              unsigned short* __restrict__ C) {
    __shared__ unsigned short As[BM * BK];  // 16 KB
    __shared__ unsigned short Bs[BN * BK];  // 16 KB
    const int tid = threadIdx.x;
    const int m0 = blockIdx.x * BM;
    const int n0 = blockIdx.y * BN;
    const int w = tid >> 6, lane = tid & 63;
    const int wm = (w >> 1) * 64, wn = (w & 1) * 64;
    const int lr = lane & 15, lg = lane >> 4;

    const int srow = tid >> 3;
    const int scol = ((tid & 7) ^ (srow & 7)) * 8;

    f32x4 acc[4][4] = {};

    for (int k0 = 0; k0 < HID; k0 += BK) {
        __syncthreads();
        #pragma unroll
        for (int r = 0; r < 4; ++r)
            gload_lds16(A + (size_t)(m0 + r * 32 + srow) * HID + k0 + scol,
                        As + r * 2048 + w * 512);
        #pragma unroll
        for (int r = 0; r < 4; ++r)
            gload_lds16(Bt + (size_t)(n0 + r * 32 + srow) * HID + k0 + scol,
                        Bs + r * 2048 + w * 512);
        __syncthreads();

        #pragma unroll
        for (int kk = 0; kk < 2; ++kk) {
            bf16x8 af[4], bfr[4];
            #pragma unroll
            for (int i = 0; i < 4; ++i) {
                int row = wm + i * 16 + lr;
                af[i] = *(const bf16x8*)(As + row * BK + (((kk * 4 + lg) ^ (row & 7)) * 8));
            }
            #pragma unroll
            for (int j = 0; j < 4; ++j) {
                int row = wn + j * 16 + lr;
                bfr[j] = *(const bf16x8*)(Bs + row * BK + (((kk * 4 + lg) ^ (row & 7)) * 8));
            }
            #pragma unroll
            for (int i = 0; i < 4; ++i)
                #pragma unroll
                for (int j = 0; j < 4; ++j)
                    acc[i][j] = __builtin_amdgcn_mfma_f32_16x16x32_bf16(af[i], bfr[j], acc[i][j], 0, 0, 0);
        }
    }

    #pragma unroll
    for (int i = 0; i < 4; ++i) {
        const int grow = m0 + wm + i * 16 + lg * 4;
        #pragma unroll
        for (int j = 0; j < 4; ++j) {
            const int gcol = n0 + wn + j * 16 + lr;
            const float bv = bias[gcol];
            #pragma unroll
            for (int rr = 0; rr < 4; ++rr)
                C[(size_t)(grow + rr) * HID + gcol] = f2bf(acc[i][j][rr] + bv);
        }
    }
}

// ---------------- GraphNorm stats: per-segment partials (no atomics) ----------------
__global__ __launch_bounds__(256) void k_gstats(const unsigned short* __restrict__ r,
                                                const int* __restrict__ gs,
                                                float* __restrict__ psum, float* __restrict__ psq) {
    int g = blockIdx.x;
    int seg = blockIdx.y;
    int s = gs[g], e = gs[g + 1];
    int c = threadIdx.x * 2;
    float s0 = 0.f, s1 = 0.f, q0 = 0.f, q1 = 0.f;
    for (int n = s + seg; n < e; n += 8) {
        ushort2 v = *(const ushort2*)(r + (size_t)n * HID + c);
        float v0 = bf2f(v.x), v1 = bf2f(v.y);
        s0 += v0; s1 += v1; q0 += v0 * v0; q1 += v1 * v1;
    }
    size_t o = ((size_t)seg * NG + g) * HID + c;
    *(float2*)(psum + o) = make_float2(s0, s1);
    *(float2*)(psq + o) = make_float2(q0, q1);
}

// ---------------- GraphNorm apply + ReLU + residual, gred folded in ----------------
// grid (NG, 8), 128 threads x 4 channels. Each block sums the 8 partials for its
// graph (same order as old k_gred -> bit-identical stats), then applies to its nodes.
__global__ __launch_bounds__(128) void k_gapply(const unsigned short* __restrict__ r,
                                                unsigned short* __restrict__ h_bf,
                                                unsigned char* __restrict__ h_f8,
                                                const int* __restrict__ gs,
                                                const float* __restrict__ rcnt,
                                                const float* __restrict__ psum, const float* __restrict__ psq,
                                                const float* __restrict__ gw, const float* __restrict__ gb,
                                                const float* __restrict__ gms) {
    int g = blockIdx.x;
    int seg = blockIdx.y;
    int s = gs[g], e = gs[g + 1];
    int c = threadIdx.x * 4;
    float rc = rcnt[g];
    float sm[4] = {0.f, 0.f, 0.f, 0.f}, sq[4] = {0.f, 0.f, 0.f, 0.f};
    #pragma unroll
    for (int k = 0; k < 8; ++k) {
        const float4 a = *(const float4*)(psum + ((size_t)k * NG + g) * HID + c);
        const float4 b = *(const float4*)(psq + ((size_t)k * NG + g) * HID + c);
        sm[0] += a.x; sm[1] += a.y; sm[2] += a.z; sm[3] += a.w;
        sq[0] += b.x; sq[1] += b.y; sq[2] += b.z; sq[3] += b.w;
    }
    const float4 ms = *(const float4*)(gms + c);
    const float4 gwv = *(const float4*)(gw + c);
    const float4 gbv = *(const float4*)(gb + c);
    float am[4], wgt[4], bb[4] = {gbv.x, gbv.y, gbv.z, gbv.w};
    float msv[4] = {ms.x, ms.y, ms.z, ms.w};
    float gwa[4] = {gwv.x, gwv.y, gwv.z, gwv.w};
    #pragma unroll
    for (int k = 0; k < 4; ++k) {
        float mean = sm[k] * rc;
        am[k] = msv[k] * mean;
        float var = sq[k] * rc - 2.f * am[k] * mean + am[k] * am[k];
        wgt[k] = gwa[k] * rsqrtf(var + 1e-6f);
    }
    for (int n = s + seg; n < e; n += 8) {
        const ushort4 rv4 = *(const ushort4*)(r + (size_t)n * HID + c);
        const ushort4 hv4 = *(const ushort4*)(h_bf + (size_t)n * HID + c);
        float rv[4] = {bf2f(rv4.x), bf2f(rv4.y), bf2f(rv4.z), bf2f(rv4.w)};
        float hv[4] = {bf2f(hv4.x), bf2f(hv4.y), bf2f(hv4.z), bf2f(hv4.w)};
        float outv[4];
        #pragma unroll
        for (int k = 0; k < 4; ++k) {
            float v = (rv[k] - am[k]) * wgt[k] + bb[k];
            v = fmaxf(v, 0.f);
            outv[k] = v + hv[k];
        }
        ushort4 pk;
        pk.x = f2bf(outv[0]); pk.y = f2bf(outv[1]); pk.z = f2bf(outv[2]); pk.w = f2bf(outv[3]);
        *(ushort4*)(h_bf + (size_t)n * HID + c) = pk;
        *(unsigned int*)(h_f8 + (size_t)n * HID + c) = f8pk4(outv[0], outv[1], outv[2], outv[3]);
    }
}

// ---------------- Last layer: apply + residual + pool partials, gred folded in ----------------
__global__ __launch_bounds__(128) void k_gpool(const unsigned short* __restrict__ r,
                                               const unsigned short* __restrict__ h_bf,
                                               const int* __restrict__ gs,
                                               const float* __restrict__ rcnt,
                                               const float* __restrict__ psum, const float* __restrict__ psq,
                                               const float* __restrict__ gw, const float* __restrict__ gb,
                                               const float* __restrict__ gms,
                                               float* __restrict__ ppool) {
    int g = blockIdx.x;
    int seg = blockIdx.y;
    int s = gs[g], e = gs[g + 1];
    int c = threadIdx.x * 4;
    float rc = rcnt[g];
    float sm[4] = {0.f, 0.f, 0.f, 0.f}, sq[4] = {0.f, 0.f, 0.f, 0.f};
    #pragma unroll
    for (int k = 0; k < 8; ++k) {
        const float4 a = *(const float4*)(psum + ((size_t)k * NG + g) * HID + c);
        const float4 b = *(const float4*)(psq + ((size_t)k * NG + g) * HID + c);
        sm[0] += a.x; sm[1] += a.y; sm[2] += a.z; sm[3] += a.w;
        sq[0] += b.x; sq[1] += b.y; sq[2] += b.z; sq[3] += b.w;
    }
    const float4 ms = *(const float4*)(gms + c);
    const float4 gwv = *(const float4*)(gw + c);
    const float4 gbv = *(const float4*)(gb + c);
    float am[4], wgt[4], bb[4] = {gbv.x, gbv.y, gbv.z, gbv.w};
    float msv[4] = {ms.x, ms.y, ms.z, ms.w};
    float gwa[4] = {gwv.x, gwv.y, gwv.z, gwv.w};
    #pragma unroll
    for (int k = 0; k < 4; ++k) {
        float mean = sm[k] * rc;
        am[k] = msv[k] * mean;
        float var = sq[k] * rc - 2.f * am[k] * mean + am[k] * am[k];
        wgt[k] = gwa[k] * rsqrtf(var + 1e-6f);
    }
    float p[4] = {0.f, 0.f, 0.f, 0.f};
    for (int n = s + seg; n < e; n += 8) {
        const ushort4 rv4 = *(const ushort4*)(r + (size_t)n * HID + c);
        const ushort4 hv4 = *(const ushort4*)(h_bf + (size_t)n * HID + c);
        float rv[4] = {bf2f(rv4.x), bf2f(rv4.y), bf2f(rv4.z), bf2f(rv4.w)};
        float hv[4] = {bf2f(hv4.x), bf2f(hv4.y), bf2f(hv4.z), bf2f(hv4.w)};
        #pragma unroll
        for (int k = 0; k < 4; ++k)
            p[k] += (rv[k] - am[k]) * wgt[k] + bb[k] + hv[k];
    }
    size_t o = ((size_t)seg * NG + g) * HID + c;
    *(float4*)(ppool + o) = make_float4(p[0], p[1], p[2], p[3]);
}

// ---------------- Final projection (folds 8 pool partials) ----------------
__global__ __launch_bounds__(128) void k_proj(const float* __restrict__ ppool,
                                              const float* __restrict__ Wp,
                                              const float* __restrict__ bp, float* __restrict__ out) {
    int g = blockIdx.x;
    int tid = threadIdx.x;
    __shared__ float pr[HID];
    {
        int c = tid * 4;
        float4 sv = make_float4(0.f, 0.f, 0.f, 0.f);
        #pragma unroll
        for (int seg = 0; seg < 8; ++seg) {
            const float4 v = *(const float4*)(ppool + ((size_t)seg * NG + g) * HID + c);
            sv.x += v.x; sv.y += v.y; sv.z += v.z; sv.w += v.w;
        }
        *(float4*)(pr + c) = sv;
    }
    __syncthreads();
    int o = tid;
    float acc = bp[o];
    #pragma unroll 8
    for (int k = 0; k < HID; ++k) acc += pr[k] * Wp[k * NOUT + o];
    out[g * NOUT + o] = acc;
}

extern "C" void kernel_launch(void* const* d_in, const int* in_sizes, int n_in,
                              void* d_out, int out_size, void* d_ws, size_t ws_size,
                              hipStream_t stream) {
    const int*   h_node = (const int*)d_in[0];
    const int*   h_edge = (const int*)d_in[1];
    const int*   src    = (const int*)d_in[2];
    const int*   dst    = (const int*)d_in[3];
    const int*   gid    = (const int*)d_in[4];
    const float* aemb   = (const float*)d_in[5];
    const float* bemb   = (const float*)d_in[6];
    const float* W      = (const float*)d_in[7];
    const float* bias   = (const float*)d_in[8];
    const float* gnw    = (const float*)d_in[9];
    const float* gnb    = (const float*)d_in[10];
    const float* gnms   = (const float*)d_in[11];
    const float* Wp     = (const float*)d_in[12];
    const float* bp     = (const float*)d_in[13];
    float* out = (float*)d_out;

    char* ws = (char*)d_ws;
    size_t off = 0;
    auto alloc = [&](size_t bytes) -> char* {
        char* p = ws + off;
        off += (bytes + 255) & ~(size_t)255;
        return p;
    };
    // zero-group first (one contiguous memset): cnt | fc
    int* cnt            = (int*)alloc((size_t)N_NODES * 4);
    int* fc             = (int*)alloc((size_t)N_NODES * 4);
    size_t zbytes = off;

    unsigned short* h_bf= (unsigned short*)alloc((size_t)N_NODES * HID * 2);
    unsigned char* h_f8 = (unsigned char*)alloc((size_t)N_NODES * HID);
    unsigned short* rbf = (unsigned short*)alloc((size_t)N_NODES * HID * 2);
    unsigned short* t   = (unsigned short*)alloc((size_t)N_NODES * HID * 2);
    unsigned short* Wt  = (unsigned short*)alloc((size_t)NL * HID * HID * 2);
    unsigned char* ctab8= (unsigned char*)alloc((size_t)NL * 512 * HID);
    int2* ep            = (int2*)alloc((size_t)N_EDGES * 8);
    int* rs             = (int*)alloc((size_t)(N_NODES + 1) * 4);
    int* gs             = (int*)alloc((size_t)(NG + 1) * 4);
    float* rcnt         = (float*)alloc((size_t)NG * 4);
    float* pstat        = (float*)alloc((size_t)2 * 8 * NG * HID * 4);
    float* ppool        = (float*)alloc((size_t)8 * NG * HID * 4);
    float* psum = pstat;
    float* psq  = pstat + (size_t)8 * NG * HID;

    hipMemsetAsync(cnt, 0, zbytes, stream);
    k_prep<<<17409, 256, 0, stream>>>(h_node, aemb, h_bf, h_f8, dst, cnt, W, Wt, bemb, ctab8,
                                      gid, gs, rcnt);
    k_scan<<<1, 256, 0, stream>>>(cnt, rs);
    k_fillep<<<N_EDGES / 256, 256, 0, stream>>>(dst, rs, fc, src, h_edge, ep);

    for (int i = 0; i < NL; ++i) {
        k_neigh<<<8192, 256, 0, stream>>>(h_f8, h_bf, ep, rs,
                                          ctab8 + (size_t)i * 512 * HID, t);
        dim3 gg(N_NODES / BM, HID / BN);
        k_gemm<<<gg, 256, 0, stream>>>(t, Wt + (size_t)i * HID * HID, bias + i * HID, rbf);
        k_gstats<<<dim3(NG, 8), 256, 0, stream>>>(rbf, gs, psum, psq);
        if (i < NL - 1) {
            k_gapply<<<dim3(NG, 8), 128, 0, stream>>>(rbf, h_bf, h_f8, gs, rcnt, psum, psq,
                                                      gnw + i * HID, gnb + i * HID, gnms + i * HID);
        } else {
            k_gpool<<<dim3(NG, 8), 128, 0, stream>>>(rbf, h_bf, gs, rcnt, psum, psq,
                                                     gnw + i * HID, gnb + i * HID, gnms + i * HID,
                                                     ppool);
        }
    }
    k_proj<<<NG, NOUT, 0, stream>>>(ppool, Wp, bp, out);
}

// Round 15
// 350.124 us; speedup vs baseline: 1.1961x; 1.1961x over previous
//
#include <hip/hip_runtime.h>

#define N_NODES 16384
#define N_EDGES 262144
#define HID 512
#define NG 256
#define NL 4
#define NOUT 128

typedef __attribute__((ext_vector_type(8))) short bf16x8;
typedef __attribute__((ext_vector_type(4))) float f32x4;
typedef __attribute__((ext_vector_type(8))) unsigned short u16x8;

static __device__ __forceinline__ unsigned short f2bf(float f) {
    unsigned int u = __float_as_uint(f);
    unsigned int r = (u + 0x7fffu + ((u >> 16) & 1u)) >> 16;
    return (unsigned short)r;
}
static __device__ __forceinline__ float bf2f(unsigned short s) {
    return __uint_as_float(((unsigned int)s) << 16);
}
// pack 4 floats -> 4 fp8 e4m3 bytes in a u32 (HW cvt)
static __device__ __forceinline__ unsigned int f8pk4(float a, float b, float c, float d) {
    int r = __builtin_amdgcn_cvt_pk_fp8_f32(a, b, 0, false);
    r = __builtin_amdgcn_cvt_pk_fp8_f32(c, d, r, true);
    return (unsigned int)r;
}
// decode 4+4 fp8 bytes (two u32 words) and accumulate into a[0..3] (literal selectors)
static __device__ __forceinline__ void dec8(unsigned int wa, unsigned int wb, float* a) {
    a[0] += __builtin_amdgcn_cvt_f32_fp8(wa, 0) + __builtin_amdgcn_cvt_f32_fp8(wb, 0);
    a[1] += __builtin_amdgcn_cvt_f32_fp8(wa, 1) + __builtin_amdgcn_cvt_f32_fp8(wb, 1);
    a[2] += __builtin_amdgcn_cvt_f32_fp8(wa, 2) + __builtin_amdgcn_cvt_f32_fp8(wb, 2);
    a[3] += __builtin_amdgcn_cvt_f32_fp8(wa, 3) + __builtin_amdgcn_cvt_f32_fp8(wb, 3);
}

// async 16B global -> LDS (wave-uniform LDS base + lane*16, per-lane global src)
static __device__ __forceinline__ void gload_lds16(const unsigned short* g, unsigned short* l) {
    __builtin_amdgcn_global_load_lds(
        (const __attribute__((address_space(1))) unsigned int*)(g),
        (__attribute__((address_space(3))) unsigned int*)(l), 16, 0, 0);
}

// ---------------- Fused prep: atom | count | wt | combo | gstart ----------------
__global__ __launch_bounds__(256) void k_prep(const int* __restrict__ hn, const float* __restrict__ aemb,
                                              unsigned short* __restrict__ h_bf,
                                              unsigned char* __restrict__ h_f8,
                                              const int* __restrict__ dst, int* __restrict__ cnt,
                                              const float* __restrict__ W, unsigned short* __restrict__ Wt,
                                              const float* __restrict__ bemb, unsigned char* __restrict__ ctab8,
                                              const int* __restrict__ gid, int* __restrict__ gs,
                                              float* __restrict__ rcnt) {
    const int bid = blockIdx.x;
    const int tid = threadIdx.x;
    if (bid < 8192) {  // ---- atom encoder: 2 nodes/block
        int n = bid * 2 + (tid >> 7);
        int c = (tid & 127) * 4;
        float4 acc = make_float4(0.f, 0.f, 0.f, 0.f);
        for (int f = 0; f < 9; ++f) {
            int v = hn[n * 9 + f];
            const float4 ev = *(const float4*)(aemb + (size_t)(f * 128 + v) * HID + c);
            acc.x += ev.x; acc.y += ev.y; acc.z += ev.z; acc.w += ev.w;
        }
        ushort4 pk;
        pk.x = f2bf(acc.x); pk.y = f2bf(acc.y); pk.z = f2bf(acc.z); pk.w = f2bf(acc.w);
        *(ushort4*)(h_bf + (size_t)n * HID + c) = pk;
        *(unsigned int*)(h_f8 + (size_t)n * HID + c) = f8pk4(acc.x, acc.y, acc.z, acc.w);
    } else if (bid < 9216) {  // ---- indegree count
        int e = (bid - 8192) * 256 + tid;
        atomicAdd(&cnt[dst[e]], 1);
    } else if (bid < 13312) {  // ---- W transpose + bf16
        int id = (bid - 9216) * 256 + tid;
        int l = id >> 18;
        int n = (id >> 9) & 511;
        int k = id & 511;
        Wt[id] = f2bf(W[((size_t)l << 18) + ((size_t)k << 9) + n]);
    } else if (bid < 17408) {  // ---- bond combo table (fp8)
        int id = (bid - 13312) * 256 + tid;
        int c = id & 511;
        int combo = (id >> 9) & 511;
        int l = id >> 18;
        int i0 = combo >> 6, i1 = (combo >> 3) & 7, i2 = combo & 7;
        const float* bl = bemb + (size_t)l * 3 * 8 * HID;
        float v = bl[(size_t)i0 * HID + c] + bl[(size_t)(8 + i1) * HID + c] + bl[(size_t)(16 + i2) * HID + c];
        int w = __builtin_amdgcn_cvt_pk_fp8_f32(v, 0.f, 0, false);
        ctab8[id] = (unsigned char)(w & 0xff);
    } else {  // ---- graph segment starts (gid sorted)
        int g = tid;
        int lo = 0, hi = N_NODES;
        while (lo < hi) { int mid = (lo + hi) >> 1; if (gid[mid] < g) lo = mid + 1; else hi = mid; }
        gs[g] = lo;
        if (g == 0) gs[NG] = N_NODES;
        __syncthreads();
        int e = (g == NG - 1) ? N_NODES : gs[g + 1];
        rcnt[g] = 1.0f / fmaxf((float)(e - lo), 1.0f);
    }
}

__global__ void k_scan(const int* __restrict__ cnt, int* __restrict__ rs) {
    __shared__ int spre[256];
    int t = threadIdx.x;
    int base = t * 64;
    int s = 0;
    for (int i = 0; i < 64; ++i) s += cnt[base + i];
    spre[t] = s;
    __syncthreads();
    if (t == 0) {
        int run = 0;
        for (int i = 0; i < 256; ++i) { int v = spre[i]; spre[i] = run; run += v; }
        rs[N_NODES] = run;
    }
    __syncthreads();
    int run = spre[t];
    for (int i = 0; i < 64; ++i) { rs[base + i] = run; run += cnt[base + i]; }
}

// fill CSR slots with packed edge records as fp8-ROW BYTE OFFSETS (src*512, combo*512)
__global__ void k_fillep(const int* __restrict__ dst, const int* __restrict__ rs,
                         int* __restrict__ fc, const int* __restrict__ src,
                         const int* __restrict__ hedge, int2* __restrict__ ep) {
    int e = blockIdx.x * 256 + threadIdx.x;
    int d = dst[e];
    int pos = atomicAdd(&fc[d], 1);
    int s = src[e];
    int c = hedge[e * 3 + 0] * 64 + hedge[e * 3 + 1] * 8 + hedge[e * 3 + 2];
    ep[rs[d] + pos] = make_int2(s << 9, c << 9);  // 512 B/row in fp8
}

// ---------------- Neighbor aggregate: fp8 gathers, 2 slices x 256 ch, unroll-2 ----------------
// slice s -> XCDs {4s..4s+3} (bid%8 round-robin heuristic); per-XCD-quad working set
// = 16384 x 256 x 1B = 4 MB. One node per wave: 64 lanes = 4 edge-slots x 16 ch-lanes
// (16 fp8 ch per lane). Self-term + output stay bf16. unroll-2 ONLY (unroll-4 = VGPR 68,
// occupancy 25%, +14 us -- measured twice, R9 and R14).
__global__ __launch_bounds__(256) void k_neigh(const unsigned char* __restrict__ h_f8,
                                               const unsigned short* __restrict__ h_bf,
                                               const int2* __restrict__ ep,
                                               const int* __restrict__ rs,
                                               const unsigned char* __restrict__ ctab8,
                                               unsigned short* __restrict__ t) {
    int bid = blockIdx.x;
    int slice = (bid >> 2) & 1;            // slice0 -> XCDs 0-3, slice1 -> 4-7
    int ng = (bid >> 3) * 4 + (bid & 3);   // node-group 0..4095
    int wave = threadIdx.x >> 6;
    int lane = threadIdx.x & 63;
    int eo = lane >> 4;                    // edge slot 0..3
    int cl = lane & 15;                    // channel lane (16 fp8 ch each)
    int n = ng * 4 + wave;
    int cb = slice * 256 + cl * 16;        // byte offset within 512B fp8 row
    const unsigned char* h8 = h_f8;
    const unsigned char* c8 = ctab8;
    int s = rs[n], e = rs[n + 1];
    float acc[16] = {};
    int j = s + eo;
    for (; j + 4 < e; j += 8) {  // unroll-2: slots j and j+4
        int2 p0 = ep[j];
        int2 p1 = ep[j + 4];
        uint4 wa0 = *(const uint4*)(h8 + (unsigned)(p0.x + cb));
        uint4 wb0 = *(const uint4*)(c8 + (unsigned)(p0.y + cb));
        uint4 wa1 = *(const uint4*)(h8 + (unsigned)(p1.x + cb));
        uint4 wb1 = *(const uint4*)(c8 + (unsigned)(p1.y + cb));
        dec8(wa0.x, wb0.x, acc);
        dec8(wa0.y, wb0.y, acc + 4);
        dec8(wa0.z, wb0.z, acc + 8);
        dec8(wa0.w, wb0.w, acc + 12);
        dec8(wa1.x, wb1.x, acc);
        dec8(wa1.y, wb1.y, acc + 4);
        dec8(wa1.z, wb1.z, acc + 8);
        dec8(wa1.w, wb1.w, acc + 12);
    }
    if (j < e) {
        int2 p = ep[j];
        uint4 wa = *(const uint4*)(h8 + (unsigned)(p.x + cb));
        uint4 wb = *(const uint4*)(c8 + (unsigned)(p.y + cb));
        dec8(wa.x, wb.x, acc);
        dec8(wa.y, wb.y, acc + 4);
        dec8(wa.z, wb.z, acc + 8);
        dec8(wa.w, wb.w, acc + 12);
    }
    // reduce the 4 edge-slot groups (lanes differing in bits 4,5)
    #pragma unroll
    for (int q = 0; q < 16; ++q) {
        acc[q] += __shfl_xor(acc[q], 16, 64);
        acc[q] += __shfl_xor(acc[q], 32, 64);
    }
    if (eo == 0) {
        size_t ob = (size_t)n * 1024 + slice * 512 + cl * 32;  // bf16 byte offset
        u16x8 hs0 = *(const u16x8*)((const char*)h_bf + ob);
        u16x8 hs1 = *(const u16x8*)((const char*)h_bf + ob + 16);
        float inv = 1.0f / fmaxf((float)(e - s), 1.0f);
        u16x8 pk0, pk1;
        #pragma unroll
        for (int q = 0; q < 8; ++q) {
            pk0[q] = f2bf(bf2f(hs0[q]) + acc[q] * inv);
            pk1[q] = f2bf(bf2f(hs1[q]) + acc[8 + q] * inv);
        }
        *(u16x8*)((char*)t + ob) = pk0;
        *(u16x8*)((char*)t + ob + 16) = pk1;
    }
}

// ---------------- GEMM: r_bf[M,512] = bf16(A @ W + bias), 128x128 tile ----------------
#define BM 128
#define BN 128
#define BK 64

__global__ __launch_bounds__(256) void k_gemm(const unsigned short* __restrict__ A,
                                              const unsigned short* __restrict__ Bt,
                                              const float* __restrict__ bias,
                                              unsigned short* __restrict__ C) {
    __shared__ unsigned short As[BM * BK];  // 16 KB
    __shared__ unsigned short Bs[BN * BK];  // 16 KB
    const int tid = threadIdx.x;
    const int m0 = blockIdx.x * BM;
    const int n0 = blockIdx.y * BN;
    const int w = tid >> 6, lane = tid & 63;
    const int wm = (w >> 1) * 64, wn = (w & 1) * 64;
    const int lr = lane & 15, lg = lane >> 4;

    const int srow = tid >> 3;
    const int scol = ((tid & 7) ^ (srow & 7)) * 8;

    f32x4 acc[4][4] = {};

    for (int k0 = 0; k0 < HID; k0 += BK) {
        __syncthreads();
        #pragma unroll
        for (int r = 0; r < 4; ++r)
            gload_lds16(A + (size_t)(m0 + r * 32 + srow) * HID + k0 + scol,
                        As + r * 2048 + w * 512);
        #pragma unroll
        for (int r = 0; r < 4; ++r)
            gload_lds16(Bt + (size_t)(n0 + r * 32 + srow) * HID + k0 + scol,
                        Bs + r * 2048 + w * 512);
        __syncthreads();

        #pragma unroll
        for (int kk = 0; kk < 2; ++kk) {
            bf16x8 af[4], bfr[4];
            #pragma unroll
            for (int i = 0; i < 4; ++i) {
                int row = wm + i * 16 + lr;
                af[i] = *(const bf16x8*)(As + row * BK + (((kk * 4 + lg) ^ (row & 7)) * 8));
            }
            #pragma unroll
            for (int j = 0; j < 4; ++j) {
                int row = wn + j * 16 + lr;
                bfr[j] = *(const bf16x8*)(Bs + row * BK + (((kk * 4 + lg) ^ (row & 7)) * 8));
            }
            #pragma unroll
            for (int i = 0; i < 4; ++i)
                #pragma unroll
                for (int j = 0; j < 4; ++j)
                    acc[i][j] = __builtin_amdgcn_mfma_f32_16x16x32_bf16(af[i], bfr[j], acc[i][j], 0, 0, 0);
        }
    }

    #pragma unroll
    for (int i = 0; i < 4; ++i) {
        const int grow = m0 + wm + i * 16 + lg * 4;
        #pragma unroll
        for (int j = 0; j < 4; ++j) {
            const int gcol = n0 + wn + j * 16 + lr;
            const float bv = bias[gcol];
            #pragma unroll
            for (int rr = 0; rr < 4; ++rr)
                C[(size_t)(grow + rr) * HID + gcol] = f2bf(acc[i][j][rr] + bv);
        }
    }
}

// ---------------- GraphNorm stats: per-segment partials (no atomics) ----------------
__global__ __launch_bounds__(256) void k_gstats(const unsigned short* __restrict__ r,
                                                const int* __restrict__ gs,
                                                float* __restrict__ psum, float* __restrict__ psq) {
    int g = blockIdx.x;
    int seg = blockIdx.y;
    int s = gs[g], e = gs[g + 1];
    int c = threadIdx.x * 2;
    float s0 = 0.f, s1 = 0.f, q0 = 0.f, q1 = 0.f;
    for (int n = s + seg; n < e; n += 8) {
        ushort2 v = *(const ushort2*)(r + (size_t)n * HID + c);
        float v0 = bf2f(v.x), v1 = bf2f(v.y);
        s0 += v0; s1 += v1; q0 += v0 * v0; q1 += v1 * v1;
    }
    size_t o = ((size_t)seg * NG + g) * HID + c;
    *(float2*)(psum + o) = make_float2(s0, s1);
    *(float2*)(psq + o) = make_float2(q0, q1);
}

// ---------------- GraphNorm apply + ReLU + residual, gred folded in ----------------
// grid (NG, 8), 128 threads x 4 channels. Each block sums the 8 partials for its
// graph (same order as old k_gred -> bit-identical stats), then applies to its nodes.
__global__ __launch_bounds__(128) void k_gapply(const unsigned short* __restrict__ r,
                                                unsigned short* __restrict__ h_bf,
                                                unsigned char* __restrict__ h_f8,
                                                const int* __restrict__ gs,
                                                const float* __restrict__ rcnt,
                                                const float* __restrict__ psum, const float* __restrict__ psq,
                                                const float* __restrict__ gw, const float* __restrict__ gb,
                                                const float* __restrict__ gms) {
    int g = blockIdx.x;
    int seg = blockIdx.y;
    int s = gs[g], e = gs[g + 1];
    int c = threadIdx.x * 4;
    float rc = rcnt[g];
    float sm[4] = {0.f, 0.f, 0.f, 0.f}, sq[4] = {0.f, 0.f, 0.f, 0.f};
    #pragma unroll
    for (int k = 0; k < 8; ++k) {
        const float4 a = *(const float4*)(psum + ((size_t)k * NG + g) * HID + c);
        const float4 b = *(const float4*)(psq + ((size_t)k * NG + g) * HID + c);
        sm[0] += a.x; sm[1] += a.y; sm[2] += a.z; sm[3] += a.w;
        sq[0] += b.x; sq[1] += b.y; sq[2] += b.z; sq[3] += b.w;
    }
    const float4 ms = *(const float4*)(gms + c);
    const float4 gwv = *(const float4*)(gw + c);
    const float4 gbv = *(const float4*)(gb + c);
    float am[4], wgt[4], bb[4] = {gbv.x, gbv.y, gbv.z, gbv.w};
    float msv[4] = {ms.x, ms.y, ms.z, ms.w};
    float gwa[4] = {gwv.x, gwv.y, gwv.z, gwv.w};
    #pragma unroll
    for (int k = 0; k < 4; ++k) {
        float mean = sm[k] * rc;
        am[k] = msv[k] * mean;
        float var = sq[k] * rc - 2.f * am[k] * mean + am[k] * am[k];
        wgt[k] = gwa[k] * rsqrtf(var + 1e-6f);
    }
    for (int n = s + seg; n < e; n += 8) {
        const ushort4 rv4 = *(const ushort4*)(r + (size_t)n * HID + c);
        const ushort4 hv4 = *(const ushort4*)(h_bf + (size_t)n * HID + c);
        float rv[4] = {bf2f(rv4.x), bf2f(rv4.y), bf2f(rv4.z), bf2f(rv4.w)};
        float hv[4] = {bf2f(hv4.x), bf2f(hv4.y), bf2f(hv4.z), bf2f(hv4.w)};
        float outv[4];
        #pragma unroll
        for (int k = 0; k < 4; ++k) {
            float v = (rv[k] - am[k]) * wgt[k] + bb[k];
            v = fmaxf(v, 0.f);
            outv[k] = v + hv[k];
        }
        ushort4 pk;
        pk.x = f2bf(outv[0]); pk.y = f2bf(outv[1]); pk.z = f2bf(outv[2]); pk.w = f2bf(outv[3]);
        *(ushort4*)(h_bf + (size_t)n * HID + c) = pk;
        *(unsigned int*)(h_f8 + (size_t)n * HID + c) = f8pk4(outv[0], outv[1], outv[2], outv[3]);
    }
}

// ---------------- Last layer: apply + residual + pool partials, gred folded in ----------------
__global__ __launch_bounds__(128) void k_gpool(const unsigned short* __restrict__ r,
                                               const unsigned short* __restrict__ h_bf,
                                               const int* __restrict__ gs,
                                               const float* __restrict__ rcnt,
                                               const float* __restrict__ psum, const float* __restrict__ psq,
                                               const float* __restrict__ gw, const float* __restrict__ gb,
                                               const float* __restrict__ gms,
                                               float* __restrict__ ppool) {
    int g = blockIdx.x;
    int seg = blockIdx.y;
    int s = gs[g], e = gs[g + 1];
    int c = threadIdx.x * 4;
    float rc = rcnt[g];
    float sm[4] = {0.f, 0.f, 0.f, 0.f}, sq[4] = {0.f, 0.f, 0.f, 0.f};
    #pragma unroll
    for (int k = 0; k < 8; ++k) {
        const float4 a = *(const float4*)(psum + ((size_t)k * NG + g) * HID + c);
        const float4 b = *(const float4*)(psq + ((size_t)k * NG + g) * HID + c);
        sm[0] += a.x; sm[1] += a.y; sm[2] += a.z; sm[3] += a.w;
        sq[0] += b.x; sq[1] += b.y; sq[2] += b.z; sq[3] += b.w;
    }
    const float4 ms = *(const float4*)(gms + c);
    const float4 gwv = *(const float4*)(gw + c);
    const float4 gbv = *(const float4*)(gb + c);
    float am[4], wgt[4], bb[4] = {gbv.x, gbv.y, gbv.z, gbv.w};
    float msv[4] = {ms.x, ms.y, ms.z, ms.w};
    float gwa[4] = {gwv.x, gwv.y, gwv.z, gwv.w};
    #pragma unroll
    for (int k = 0; k < 4; ++k) {
        float mean = sm[k] * rc;
        am[k] = msv[k] * mean;
        float var = sq[k] * rc - 2.f * am[k] * mean + am[k] * am[k];
        wgt[k] = gwa[k] * rsqrtf(var + 1e-6f);
    }
    float p[4] = {0.f, 0.f, 0.f, 0.f};
    for (int n = s + seg; n < e; n += 8) {
        const ushort4 rv4 = *(const ushort4*)(r + (size_t)n * HID + c);
        const ushort4 hv4 = *(const ushort4*)(h_bf + (size_t)n * HID + c);
        float rv[4] = {bf2f(rv4.x), bf2f(rv4.y), bf2f(rv4.z), bf2f(rv4.w)};
        float hv[4] = {bf2f(hv4.x), bf2f(hv4.y), bf2f(hv4.z), bf2f(hv4.w)};
        #pragma unroll
        for (int k = 0; k < 4; ++k)
            p[k] += (rv[k] - am[k]) * wgt[k] + bb[k] + hv[k];
    }
    size_t o = ((size_t)seg * NG + g) * HID + c;
    *(float4*)(ppool + o) = make_float4(p[0], p[1], p[2], p[3]);
}

// ---------------- Final projection (folds 8 pool partials) ----------------
__global__ __launch_bounds__(128) void k_proj(const float* __restrict__ ppool,
                                              const float* __restrict__ Wp,
                                              const float* __restrict__ bp, float* __restrict__ out) {
    int g = blockIdx.x;
    int tid = threadIdx.x;
    __shared__ float pr[HID];
    {
        int c = tid * 4;
        float4 sv = make_float4(0.f, 0.f, 0.f, 0.f);
        #pragma unroll
        for (int seg = 0; seg < 8; ++seg) {
            const float4 v = *(const float4*)(ppool + ((size_t)seg * NG + g) * HID + c);
            sv.x += v.x; sv.y += v.y; sv.z += v.z; sv.w += v.w;
        }
        *(float4*)(pr + c) = sv;
    }
    __syncthreads();
    int o = tid;
    float acc = bp[o];
    #pragma unroll 8
    for (int k = 0; k < HID; ++k) acc += pr[k] * Wp[k * NOUT + o];
    out[g * NOUT + o] = acc;
}

extern "C" void kernel_launch(void* const* d_in, const int* in_sizes, int n_in,
                              void* d_out, int out_size, void* d_ws, size_t ws_size,
                              hipStream_t stream) {
    const int*   h_node = (const int*)d_in[0];
    const int*   h_edge = (const int*)d_in[1];
    const int*   src    = (const int*)d_in[2];
    const int*   dst    = (const int*)d_in[3];
    const int*   gid    = (const int*)d_in[4];
    const float* aemb   = (const float*)d_in[5];
    const float* bemb   = (const float*)d_in[6];
    const float* W      = (const float*)d_in[7];
    const float* bias   = (const float*)d_in[8];
    const float* gnw    = (const float*)d_in[9];
    const float* gnb    = (const float*)d_in[10];
    const float* gnms   = (const float*)d_in[11];
    const float* Wp     = (const float*)d_in[12];
    const float* bp     = (const float*)d_in[13];
    float* out = (float*)d_out;

    char* ws = (char*)d_ws;
    size_t off = 0;
    auto alloc = [&](size_t bytes) -> char* {
        char* p = ws + off;
        off += (bytes + 255) & ~(size_t)255;
        return p;
    };
    // zero-group first (one contiguous memset): cnt | fc
    int* cnt            = (int*)alloc((size_t)N_NODES * 4);
    int* fc             = (int*)alloc((size_t)N_NODES * 4);
    size_t zbytes = off;

    unsigned short* h_bf= (unsigned short*)alloc((size_t)N_NODES * HID * 2);
    unsigned char* h_f8 = (unsigned char*)alloc((size_t)N_NODES * HID);
    unsigned short* rbf = (unsigned short*)alloc((size_t)N_NODES * HID * 2);
    unsigned short* t   = (unsigned short*)alloc((size_t)N_NODES * HID * 2);
    unsigned short* Wt  = (unsigned short*)alloc((size_t)NL * HID * HID * 2);
    unsigned char* ctab8= (unsigned char*)alloc((size_t)NL * 512 * HID);
    int2* ep            = (int2*)alloc((size_t)N_EDGES * 8);
    int* rs             = (int*)alloc((size_t)(N_NODES + 1) * 4);
    int* gs             = (int*)alloc((size_t)(NG + 1) * 4);
    float* rcnt         = (float*)alloc((size_t)NG * 4);
    float* pstat        = (float*)alloc((size_t)2 * 8 * NG * HID * 4);
    float* ppool        = (float*)alloc((size_t)8 * NG * HID * 4);
    float* psum = pstat;
    float* psq  = pstat + (size_t)8 * NG * HID;

    hipMemsetAsync(cnt, 0, zbytes, stream);
    k_prep<<<17409, 256, 0, stream>>>(h_node, aemb, h_bf, h_f8, dst, cnt, W, Wt, bemb, ctab8,
                                      gid, gs, rcnt);
    k_scan<<<1, 256, 0, stream>>>(cnt, rs);
    k_fillep<<<N_EDGES / 256, 256, 0, stream>>>(dst, rs, fc, src, h_edge, ep);

    for (int i = 0; i < NL; ++i) {
        k_neigh<<<8192, 256, 0, stream>>>(h_f8, h_bf, ep, rs,
                                          ctab8 + (size_t)i * 512 * HID, t);
        dim3 gg(N_NODES / BM, HID / BN);
        k_gemm<<<gg, 256, 0, stream>>>(t, Wt + (size_t)i * HID * HID, bias + i * HID, rbf);
        k_gstats<<<dim3(NG, 8), 256, 0, stream>>>(rbf, gs, psum, psq);
        if (i < NL - 1) {
            k_gapply<<<dim3(NG, 8), 128, 0, stream>>>(rbf, h_bf, h_f8, gs, rcnt, psum, psq,
                                                      gnw + i * HID, gnb + i * HID, gnms + i * HID);
        } else {
            k_gpool<<<dim3(NG, 8), 128, 0, stream>>>(rbf, h_bf, gs, rcnt, psum, psq,
                                                     gnw + i * HID, gnb + i * HID, gnms + i * HID,
                                                     ppool);
        }
    }
    k_proj<<<NG, NOUT, 0, stream>>>(ppool, Wp, bp, out);
}

// Round 16
// 329.754 us; speedup vs baseline: 1.2700x; 1.0618x over previous
//
#include <hip/hip_runtime.h>

#define N_NODES 16384
#define N_EDGES 262144
#define HID 512
#define NG 256
#define NL 4
#define NOUT 128

typedef __attribute__((ext_vector_type(8))) short bf16x8;
typedef __attribute__((ext_vector_type(4))) float f32x4;
typedef __attribute__((ext_vector_type(2))) float f32x2;
typedef __attribute__((ext_vector_type(8))) unsigned short u16x8;

static __device__ __forceinline__ unsigned short f2bf(float f) {
    unsigned int u = __float_as_uint(f);
    unsigned int r = (u + 0x7fffu + ((u >> 16) & 1u)) >> 16;
    return (unsigned short)r;
}
static __device__ __forceinline__ float bf2f(unsigned short s) {
    return __uint_as_float(((unsigned int)s) << 16);
}
// pack 4 floats -> 4 fp8 e4m3 bytes in a u32 (HW cvt)
static __device__ __forceinline__ unsigned int f8pk4(float a, float b, float c, float d) {
    int r = __builtin_amdgcn_cvt_pk_fp8_f32(a, b, 0, false);
    r = __builtin_amdgcn_cvt_pk_fp8_f32(c, d, r, true);
    return (unsigned int)r;
}
// packed fp32 add (VOP3P v_pk_add_f32): 2 adds in 1 instruction (R11: compile-safe, neutral)
static __device__ __forceinline__ f32x2 pkadd(f32x2 a, f32x2 b) {
    f32x2 d;
    asm("v_pk_add_f32 %0, %1, %2" : "=v"(d) : "v"(a), "v"(b));
    return d;
}
// packed decode+accumulate: one u32 (4 fp8 ch) of h and ctab -> a[0] (ch 0,1), a[1] (ch 2,3)
// 4 pk_cvt + 4 pk_add per 4 channels = 2 VALU/ch (vs 4 with byte-wise cvt).
// Per-channel arithmetic order identical to byte-wise path: (h+c) then acc += .
static __device__ __forceinline__ void decpk(unsigned int wa, unsigned int wb, f32x2* a) {
    f32x2 hl = __builtin_amdgcn_cvt_pk_f32_fp8((int)wa, false);
    f32x2 hh = __builtin_amdgcn_cvt_pk_f32_fp8((int)wa, true);
    f32x2 cl = __builtin_amdgcn_cvt_pk_f32_fp8((int)wb, false);
    f32x2 ch = __builtin_amdgcn_cvt_pk_f32_fp8((int)wb, true);
    a[0] = pkadd(a[0], pkadd(hl, cl));
    a[1] = pkadd(a[1], pkadd(hh, ch));
}

// async 16B global -> LDS (wave-uniform LDS base + lane*16, per-lane global src)
static __device__ __forceinline__ void gload_lds16(const unsigned short* g, unsigned short* l) {
    __builtin_amdgcn_global_load_lds(
        (const __attribute__((address_space(1))) unsigned int*)(g),
        (__attribute__((address_space(3))) unsigned int*)(l), 16, 0, 0);
}

// ---------------- Fused prep: atom | count | wt | combo | gstart ----------------
__global__ __launch_bounds__(256) void k_prep(const int* __restrict__ hn, const float* __restrict__ aemb,
                                              unsigned short* __restrict__ h_bf,
                                              unsigned char* __restrict__ h_f8,
                                              const int* __restrict__ dst, int* __restrict__ cnt,
                                              const float* __restrict__ W, unsigned short* __restrict__ Wt,
                                              const float* __restrict__ bemb, unsigned char* __restrict__ ctab8,
                                              const int* __restrict__ gid, int* __restrict__ gs,
                                              float* __restrict__ rcnt) {
    const int bid = blockIdx.x;
    const int tid = threadIdx.x;
    if (bid < 8192) {  // ---- atom encoder: 2 nodes/block
        int n = bid * 2 + (tid >> 7);
        int c = (tid & 127) * 4;
        float4 acc = make_float4(0.f, 0.f, 0.f, 0.f);
        for (int f = 0; f < 9; ++f) {
            int v = hn[n * 9 + f];
            const float4 ev = *(const float4*)(aemb + (size_t)(f * 128 + v) * HID + c);
            acc.x += ev.x; acc.y += ev.y; acc.z += ev.z; acc.w += ev.w;
        }
        ushort4 pk;
        pk.x = f2bf(acc.x); pk.y = f2bf(acc.y); pk.z = f2bf(acc.z); pk.w = f2bf(acc.w);
        *(ushort4*)(h_bf + (size_t)n * HID + c) = pk;
        *(unsigned int*)(h_f8 + (size_t)n * HID + c) = f8pk4(acc.x, acc.y, acc.z, acc.w);
    } else if (bid < 9216) {  // ---- indegree count
        int e = (bid - 8192) * 256 + tid;
        atomicAdd(&cnt[dst[e]], 1);
    } else if (bid < 13312) {  // ---- W transpose + bf16
        int id = (bid - 9216) * 256 + tid;
        int l = id >> 18;
        int n = (id >> 9) & 511;
        int k = id & 511;
        Wt[id] = f2bf(W[((size_t)l << 18) + ((size_t)k << 9) + n]);
    } else if (bid < 17408) {  // ---- bond combo table (fp8)
        int id = (bid - 13312) * 256 + tid;
        int c = id & 511;
        int combo = (id >> 9) & 511;
        int l = id >> 18;
        int i0 = combo >> 6, i1 = (combo >> 3) & 7, i2 = combo & 7;
        const float* bl = bemb + (size_t)l * 3 * 8 * HID;
        float v = bl[(size_t)i0 * HID + c] + bl[(size_t)(8 + i1) * HID + c] + bl[(size_t)(16 + i2) * HID + c];
        int w = __builtin_amdgcn_cvt_pk_fp8_f32(v, 0.f, 0, false);
        ctab8[id] = (unsigned char)(w & 0xff);
    } else {  // ---- graph segment starts (gid sorted)
        int g = tid;
        int lo = 0, hi = N_NODES;
        while (lo < hi) { int mid = (lo + hi) >> 1; if (gid[mid] < g) lo = mid + 1; else hi = mid; }
        gs[g] = lo;
        if (g == 0) gs[NG] = N_NODES;
        __syncthreads();
        int e = (g == NG - 1) ? N_NODES : gs[g + 1];
        rcnt[g] = 1.0f / fmaxf((float)(e - lo), 1.0f);
    }
}

__global__ void k_scan(const int* __restrict__ cnt, int* __restrict__ rs) {
    __shared__ int spre[256];
    int t = threadIdx.x;
    int base = t * 64;
    int s = 0;
    for (int i = 0; i < 64; ++i) s += cnt[base + i];
    spre[t] = s;
    __syncthreads();
    if (t == 0) {
        int run = 0;
        for (int i = 0; i < 256; ++i) { int v = spre[i]; spre[i] = run; run += v; }
        rs[N_NODES] = run;
    }
    __syncthreads();
    int run = spre[t];
    for (int i = 0; i < 64; ++i) { rs[base + i] = run; run += cnt[base + i]; }
}

// fill CSR slots with packed edge records as fp8-ROW BYTE OFFSETS (src*512, combo*512)
__global__ void k_fillep(const int* __restrict__ dst, const int* __restrict__ rs,
                         int* __restrict__ fc, const int* __restrict__ src,
                         const int* __restrict__ hedge, int2* __restrict__ ep) {
    int e = blockIdx.x * 256 + threadIdx.x;
    int d = dst[e];
    int pos = atomicAdd(&fc[d], 1);
    int s = src[e];
    int c = hedge[e * 3 + 0] * 64 + hedge[e * 3 + 1] * 8 + hedge[e * 3 + 2];
    ep[rs[d] + pos] = make_int2(s << 9, c << 9);  // 512 B/row in fp8
}

// ---------------- Neighbor aggregate: fp8 gathers, packed cvt/add, unroll-2 ----------------
// slice s -> XCDs {4s..4s+3} (bid%8 round-robin heuristic); per-XCD-quad working set
// = 16384 x 256 x 1B = 4 MB. One node per wave: 64 lanes = 4 edge-slots x 16 ch-lanes
// (16 fp8 ch per lane). Self-term + output stay bf16. unroll-2 ONLY (unroll-4 = VGPR 68,
// occupancy 25%, +14 us -- measured twice, R9 and R14).
__global__ __launch_bounds__(256) void k_neigh(const unsigned char* __restrict__ h_f8,
                                               const unsigned short* __restrict__ h_bf,
                                               const int2* __restrict__ ep,
                                               const int* __restrict__ rs,
                                               const unsigned char* __restrict__ ctab8,
                                               unsigned short* __restrict__ t) {
    int bid = blockIdx.x;
    int slice = (bid >> 2) & 1;            // slice0 -> XCDs 0-3, slice1 -> 4-7
    int ng = (bid >> 3) * 4 + (bid & 3);   // node-group 0..4095
    int wave = threadIdx.x >> 6;
    int lane = threadIdx.x & 63;
    int eo = lane >> 4;                    // edge slot 0..3
    int cl = lane & 15;                    // channel lane (16 fp8 ch each)
    int n = ng * 4 + wave;
    int cb = slice * 256 + cl * 16;        // byte offset within 512B fp8 row
    const unsigned char* h8 = h_f8;
    const unsigned char* c8 = ctab8;
    int s = rs[n], e = rs[n + 1];
    f32x2 acc2[8] = {};                    // ch = 2k, 2k+1 in acc2[k]
    int j = s + eo;
    for (; j + 4 < e; j += 8) {  // unroll-2: slots j and j+4
        int2 p0 = ep[j];
        int2 p1 = ep[j + 4];
        uint4 wa0 = *(const uint4*)(h8 + (unsigned)(p0.x + cb));
        uint4 wb0 = *(const uint4*)(c8 + (unsigned)(p0.y + cb));
        uint4 wa1 = *(const uint4*)(h8 + (unsigned)(p1.x + cb));
        uint4 wb1 = *(const uint4*)(c8 + (unsigned)(p1.y + cb));
        decpk(wa0.x, wb0.x, acc2);
        decpk(wa0.y, wb0.y, acc2 + 2);
        decpk(wa0.z, wb0.z, acc2 + 4);
        decpk(wa0.w, wb0.w, acc2 + 6);
        decpk(wa1.x, wb1.x, acc2);
        decpk(wa1.y, wb1.y, acc2 + 2);
        decpk(wa1.z, wb1.z, acc2 + 4);
        decpk(wa1.w, wb1.w, acc2 + 6);
    }
    if (j < e) {
        int2 p = ep[j];
        uint4 wa = *(const uint4*)(h8 + (unsigned)(p.x + cb));
        uint4 wb = *(const uint4*)(c8 + (unsigned)(p.y + cb));
        decpk(wa.x, wb.x, acc2);
        decpk(wa.y, wb.y, acc2 + 2);
        decpk(wa.z, wb.z, acc2 + 4);
        decpk(wa.w, wb.w, acc2 + 6);
    }
    // reduce the 4 edge-slot groups (lanes differing in bits 4,5)
    #pragma unroll
    for (int k = 0; k < 8; ++k) {
        acc2[k].x += __shfl_xor(acc2[k].x, 16, 64);
        acc2[k].y += __shfl_xor(acc2[k].y, 16, 64);
        acc2[k].x += __shfl_xor(acc2[k].x, 32, 64);
        acc2[k].y += __shfl_xor(acc2[k].y, 32, 64);
    }
    if (eo == 0) {
        size_t ob = (size_t)n * 1024 + slice * 512 + cl * 32;  // bf16 byte offset
        u16x8 hs0 = *(const u16x8*)((const char*)h_bf + ob);
        u16x8 hs1 = *(const u16x8*)((const char*)h_bf + ob + 16);
        float inv = 1.0f / fmaxf((float)(e - s), 1.0f);
        u16x8 pk0, pk1;
        #pragma unroll
        for (int q = 0; q < 8; ++q) {
            float a0 = (q & 1) ? acc2[q >> 1].y : acc2[q >> 1].x;
            float a1 = (q & 1) ? acc2[4 + (q >> 1)].y : acc2[4 + (q >> 1)].x;
            pk0[q] = f2bf(bf2f(hs0[q]) + a0 * inv);
            pk1[q] = f2bf(bf2f(hs1[q]) + a1 * inv);
        }
        *(u16x8*)((char*)t + ob) = pk0;
        *(u16x8*)((char*)t + ob + 16) = pk1;
    }
}

// ---------------- GEMM: r_bf[M,512] = bf16(A @ W + bias), 128x128 tile ----------------
#define BM 128
#define BN 128
#define BK 64

__global__ __launch_bounds__(256) void k_gemm(const unsigned short* __restrict__ A,
                                              const unsigned short* __restrict__ Bt,
                                              const float* __restrict__ bias,
                                              unsigned short* __restrict__ C) {
    __shared__ unsigned short As[BM * BK];  // 16 KB
    __shared__ unsigned short Bs[BN * BK];  // 16 KB
    const int tid = threadIdx.x;
    const int m0 = blockIdx.x * BM;
    const int n0 = blockIdx.y * BN;
    const int w = tid >> 6, lane = tid & 63;
    const int wm = (w >> 1) * 64, wn = (w & 1) * 64;
    const int lr = lane & 15, lg = lane >> 4;

    const int srow = tid >> 3;
    const int scol = ((tid & 7) ^ (srow & 7)) * 8;

    f32x4 acc[4][4] = {};

    for (int k0 = 0; k0 < HID; k0 += BK) {
        __syncthreads();
        #pragma unroll
        for (int r = 0; r < 4; ++r)
            gload_lds16(A + (size_t)(m0 + r * 32 + srow) * HID + k0 + scol,
                        As + r * 2048 + w * 512);
        #pragma unroll
        for (int r = 0; r < 4; ++r)
            gload_lds16(Bt + (size_t)(n0 + r * 32 + srow) * HID + k0 + scol,
                        Bs + r * 2048 + w * 512);
        __syncthreads();

        #pragma unroll
        for (int kk = 0; kk < 2; ++kk) {
            bf16x8 af[4], bfr[4];
            #pragma unroll
            for (int i = 0; i < 4; ++i) {
                int row = wm + i * 16 + lr;
                af[i] = *(const bf16x8*)(As + row * BK + (((kk * 4 + lg) ^ (row & 7)) * 8));
            }
            #pragma unroll
            for (int j = 0; j < 4; ++j) {
                int row = wn + j * 16 + lr;
                bfr[j] = *(const bf16x8*)(Bs + row * BK + (((kk * 4 + lg) ^ (row & 7)) * 8));
            }
            #pragma unroll
            for (int i = 0; i < 4; ++i)
                #pragma unroll
                for (int j = 0; j < 4; ++j)
                    acc[i][j] = __builtin_amdgcn_mfma_f32_16x16x32_bf16(af[i], bfr[j], acc[i][j], 0, 0, 0);
        }
    }

    #pragma unroll
    for (int i = 0; i < 4; ++i) {
        const int grow = m0 + wm + i * 16 + lg * 4;
        #pragma unroll
        for (int j = 0; j < 4; ++j) {
            const int gcol = n0 + wn + j * 16 + lr;
            const float bv = bias[gcol];
            #pragma unroll
            for (int rr = 0; rr < 4; ++rr)
                C[(size_t)(grow + rr) * HID + gcol] = f2bf(acc[i][j][rr] + bv);
        }
    }
}

// ---------------- GraphNorm stats: per-segment partials (no atomics) ----------------
__global__ __launch_bounds__(256) void k_gstats(const unsigned short* __restrict__ r,
                                                const int* __restrict__ gs,
                                                float* __restrict__ psum, float* __restrict__ psq) {
    int g = blockIdx.x;
    int seg = blockIdx.y;
    int s = gs[g], e = gs[g + 1];
    int c = threadIdx.x * 2;
    float s0 = 0.f, s1 = 0.f, q0 = 0.f, q1 = 0.f;
    for (int n = s + seg; n < e; n += 8) {
        ushort2 v = *(const ushort2*)(r + (size_t)n * HID + c);
        float v0 = bf2f(v.x), v1 = bf2f(v.y);
        s0 += v0; s1 += v1; q0 += v0 * v0; q1 += v1 * v1;
    }
    size_t o = ((size_t)seg * NG + g) * HID + c;
    *(float2*)(psum + o) = make_float2(s0, s1);
    *(float2*)(psq + o) = make_float2(q0, q1);
}

// ---------------- GraphNorm apply + ReLU + residual, gred folded in ----------------
__global__ __launch_bounds__(128) void k_gapply(const unsigned short* __restrict__ r,
                                                unsigned short* __restrict__ h_bf,
                                                unsigned char* __restrict__ h_f8,
                                                const int* __restrict__ gs,
                                                const float* __restrict__ rcnt,
                                                const float* __restrict__ psum, const float* __restrict__ psq,
                                                const float* __restrict__ gw, const float* __restrict__ gb,
                                                const float* __restrict__ gms) {
    int g = blockIdx.x;
    int seg = blockIdx.y;
    int s = gs[g], e = gs[g + 1];
    int c = threadIdx.x * 4;
    float rc = rcnt[g];
    float sm[4] = {0.f, 0.f, 0.f, 0.f}, sq[4] = {0.f, 0.f, 0.f, 0.f};
    #pragma unroll
    for (int k = 0; k < 8; ++k) {
        const float4 a = *(const float4*)(psum + ((size_t)k * NG + g) * HID + c);
        const float4 b = *(const float4*)(psq + ((size_t)k * NG + g) * HID + c);
        sm[0] += a.x; sm[1] += a.y; sm[2] += a.z; sm[3] += a.w;
        sq[0] += b.x; sq[1] += b.y; sq[2] += b.z; sq[3] += b.w;
    }
    const float4 ms = *(const float4*)(gms + c);
    const float4 gwv = *(const float4*)(gw + c);
    const float4 gbv = *(const float4*)(gb + c);
    float am[4], wgt[4], bb[4] = {gbv.x, gbv.y, gbv.z, gbv.w};
    float msv[4] = {ms.x, ms.y, ms.z, ms.w};
    float gwa[4] = {gwv.x, gwv.y, gwv.z, gwv.w};
    #pragma unroll
    for (int k = 0; k < 4; ++k) {
        float mean = sm[k] * rc;
        am[k] = msv[k] * mean;
        float var = sq[k] * rc - 2.f * am[k] * mean + am[k] * am[k];
        wgt[k] = gwa[k] * rsqrtf(var + 1e-6f);
    }
    for (int n = s + seg; n < e; n += 8) {
        const ushort4 rv4 = *(const ushort4*)(r + (size_t)n * HID + c);
        const ushort4 hv4 = *(const ushort4*)(h_bf + (size_t)n * HID + c);
        float rv[4] = {bf2f(rv4.x), bf2f(rv4.y), bf2f(rv4.z), bf2f(rv4.w)};
        float hv[4] = {bf2f(hv4.x), bf2f(hv4.y), bf2f(hv4.z), bf2f(hv4.w)};
        float outv[4];
        #pragma unroll
        for (int k = 0; k < 4; ++k) {
            float v = (rv[k] - am[k]) * wgt[k] + bb[k];
            v = fmaxf(v, 0.f);
            outv[k] = v + hv[k];
        }
        ushort4 pk;
        pk.x = f2bf(outv[0]); pk.y = f2bf(outv[1]); pk.z = f2bf(outv[2]); pk.w = f2bf(outv[3]);
        *(ushort4*)(h_bf + (size_t)n * HID + c) = pk;
        *(unsigned int*)(h_f8 + (size_t)n * HID + c) = f8pk4(outv[0], outv[1], outv[2], outv[3]);
    }
}

// ---------------- Last layer: apply + residual + pool partials, gred folded in ----------------
__global__ __launch_bounds__(128) void k_gpool(const unsigned short* __restrict__ r,
                                               const unsigned short* __restrict__ h_bf,
                                               const int* __restrict__ gs,
                                               const float* __restrict__ rcnt,
                                               const float* __restrict__ psum, const float* __restrict__ psq,
                                               const float* __restrict__ gw, const float* __restrict__ gb,
                                               const float* __restrict__ gms,
                                               float* __restrict__ ppool) {
    int g = blockIdx.x;
    int seg = blockIdx.y;
    int s = gs[g], e = gs[g + 1];
    int c = threadIdx.x * 4;
    float rc = rcnt[g];
    float sm[4] = {0.f, 0.f, 0.f, 0.f}, sq[4] = {0.f, 0.f, 0.f, 0.f};
    #pragma unroll
    for (int k = 0; k < 8; ++k) {
        const float4 a = *(const float4*)(psum + ((size_t)k * NG + g) * HID + c);
        const float4 b = *(const float4*)(psq + ((size_t)k * NG + g) * HID + c);
        sm[0] += a.x; sm[1] += a.y; sm[2] += a.z; sm[3] += a.w;
        sq[0] += b.x; sq[1] += b.y; sq[2] += b.z; sq[3] += b.w;
    }
    const float4 ms = *(const float4*)(gms + c);
    const float4 gwv = *(const float4*)(gw + c);
    const float4 gbv = *(const float4*)(gb + c);
    float am[4], wgt[4], bb[4] = {gbv.x, gbv.y, gbv.z, gbv.w};
    float msv[4] = {ms.x, ms.y, ms.z, ms.w};
    float gwa[4] = {gwv.x, gwv.y, gwv.z, gwv.w};
    #pragma unroll
    for (int k = 0; k < 4; ++k) {
        float mean = sm[k] * rc;
        am[k] = msv[k] * mean;
        float var = sq[k] * rc - 2.f * am[k] * mean + am[k] * am[k];
        wgt[k] = gwa[k] * rsqrtf(var + 1e-6f);
    }
    float p[4] = {0.f, 0.f, 0.f, 0.f};
    for (int n = s + seg; n < e; n += 8) {
        const ushort4 rv4 = *(const ushort4*)(r + (size_t)n * HID + c);
        const ushort4 hv4 = *(const ushort4*)(h_bf + (size_t)n * HID + c);
        float rv[4] = {bf2f(rv4.x), bf2f(rv4.y), bf2f(rv4.z), bf2f(rv4.w)};
        float hv[4] = {bf2f(hv4.x), bf2f(hv4.y), bf2f(hv4.z), bf2f(hv4.w)};
        #pragma unroll
        for (int k = 0; k < 4; ++k)
            p[k] += (rv[k] - am[k]) * wgt[k] + bb[k] + hv[k];
    }
    size_t o = ((size_t)seg * NG + g) * HID + c;
    *(float4*)(ppool + o) = make_float4(p[0], p[1], p[2], p[3]);
}

// ---------------- Final projection (folds 8 pool partials) ----------------
__global__ __launch_bounds__(128) void k_proj(const float* __restrict__ ppool,
                                              const float* __restrict__ Wp,
                                              const float* __restrict__ bp, float* __restrict__ out) {
    int g = blockIdx.x;
    int tid = threadIdx.x;
    __shared__ float pr[HID];
    {
        int c = tid * 4;
        float4 sv = make_float4(0.f, 0.f, 0.f, 0.f);
        #pragma unroll
        for (int seg = 0; seg < 8; ++seg) {
            const float4 v = *(const float4*)(ppool + ((size_t)seg * NG + g) * HID + c);
            sv.x += v.x; sv.y += v.y; sv.z += v.z; sv.w += v.w;
        }
        *(float4*)(pr + c) = sv;
    }
    __syncthreads();
    int o = tid;
    float acc = bp[o];
    #pragma unroll 8
    for (int k = 0; k < HID; ++k) acc += pr[k] * Wp[k * NOUT + o];
    out[g * NOUT + o] = acc;
}

extern "C" void kernel_launch(void* const* d_in, const int* in_sizes, int n_in,
                              void* d_out, int out_size, void* d_ws, size_t ws_size,
                              hipStream_t stream) {
    const int*   h_node = (const int*)d_in[0];
    const int*   h_edge = (const int*)d_in[1];
    const int*   src    = (const int*)d_in[2];
    const int*   dst    = (const int*)d_in[3];
    const int*   gid    = (const int*)d_in[4];
    const float* aemb   = (const float*)d_in[5];
    const float* bemb   = (const float*)d_in[6];
    const float* W      = (const float*)d_in[7];
    const float* bias   = (const float*)d_in[8];
    const float* gnw    = (const float*)d_in[9];
    const float* gnb    = (const float*)d_in[10];
    const float* gnms   = (const float*)d_in[11];
    const float* Wp     = (const float*)d_in[12];
    const float* bp     = (const float*)d_in[13];
    float* out = (float*)d_out;

    char* ws = (char*)d_ws;
    size_t off = 0;
    auto alloc = [&](size_t bytes) -> char* {
        char* p = ws + off;
        off += (bytes + 255) & ~(size_t)255;
        return p;
    };
    // zero-group first (one contiguous memset): cnt | fc
    int* cnt            = (int*)alloc((size_t)N_NODES * 4);
    int* fc             = (int*)alloc((size_t)N_NODES * 4);
    size_t zbytes = off;

    unsigned short* h_bf= (unsigned short*)alloc((size_t)N_NODES * HID * 2);
    unsigned char* h_f8 = (unsigned char*)alloc((size_t)N_NODES * HID);
    unsigned short* rbf = (unsigned short*)alloc((size_t)N_NODES * HID * 2);
    unsigned short* t   = (unsigned short*)alloc((size_t)N_NODES * HID * 2);
    unsigned short* Wt  = (unsigned short*)alloc((size_t)NL * HID * HID * 2);
    unsigned char* ctab8= (unsigned char*)alloc((size_t)NL * 512 * HID);
    int2* ep            = (int2*)alloc((size_t)N_EDGES * 8);
    int* rs             = (int*)alloc((size_t)(N_NODES + 1) * 4);
    int* gs             = (int*)alloc((size_t)(NG + 1) * 4);
    float* rcnt         = (float*)alloc((size_t)NG * 4);
    float* pstat        = (float*)alloc((size_t)2 * 8 * NG * HID * 4);
    float* ppool        = (float*)alloc((size_t)8 * NG * HID * 4);
    float* psum = pstat;
    float* psq  = pstat + (size_t)8 * NG * HID;

    hipMemsetAsync(cnt, 0, zbytes, stream);
    k_prep<<<17409, 256, 0, stream>>>(h_node, aemb, h_bf, h_f8, dst, cnt, W, Wt, bemb, ctab8,
                                      gid, gs, rcnt);
    k_scan<<<1, 256, 0, stream>>>(cnt, rs);
    k_fillep<<<N_EDGES / 256, 256, 0, stream>>>(dst, rs, fc, src, h_edge, ep);

    for (int i = 0; i < NL; ++i) {
        k_neigh<<<8192, 256, 0, stream>>>(h_f8, h_bf, ep, rs,
                                          ctab8 + (size_t)i * 512 * HID, t);
        dim3 gg(N_NODES / BM, HID / BN);
        k_gemm<<<gg, 256, 0, stream>>>(t, Wt + (size_t)i * HID * HID, bias + i * HID, rbf);
        k_gstats<<<dim3(NG, 8), 256, 0, stream>>>(rbf, gs, psum, psq);
        if (i < NL - 1) {
            k_gapply<<<dim3(NG, 8), 128, 0, stream>>>(rbf, h_bf, h_f8, gs, rcnt, psum, psq,
                                                      gnw + i * HID, gnb + i * HID, gnms + i * HID);
        } else {
            k_gpool<<<dim3(NG, 8), 128, 0, stream>>>(rbf, h_bf, gs, rcnt, psum, psq,
                                                     gnw + i * HID, gnb + i * HID, gnms + i * HID,
                                                     ppool);
        }
    }
    k_proj<<<NG, NOUT, 0, stream>>>(ppool, Wp, bp, out);
}